// Round 10
// baseline (51.324 us; speedup 1.0000x reference)
//
#include <hip/hip_runtime.h>
#include <hip/hip_bf16.h>
#include <math.h>

#define BB 8
#define TT 2048
#define EE 1024
#define HH 64
// 1/sqrt(64) * log2(e): fold into q so scores are in exp2 domain
#define QSCALE 0.18033688011112042f

typedef __attribute__((ext_vector_type(8))) short short8;
typedef __attribute__((ext_vector_type(4))) float f32x4;
typedef __attribute__((ext_vector_type(16))) float f32x16;
typedef __attribute__((ext_vector_type(4))) unsigned short us4;

__device__ inline unsigned short f2bf(float f) {
  union { __hip_bfloat16 h; unsigned short u; } cv;
  cv.h = __float2bfloat16(f);
  return cv.u;
}

// ---------- prep: fragment-ordered weights (16x16 frags for proj) ----------
__global__ __launch_bounds__(256) void prep_w(
    const float* __restrict__ Wk, const float* __restrict__ Wq,
    const float* __restrict__ Wv, unsigned short* __restrict__ Wf) {
  const int idx = blockIdx.x * 256 + threadIdx.x;  // 12*32*64 = 24576
  const int lane = idx & 63, ks = (idx >> 6) & 31, t = idx >> 11;
  const int q = lane & 15, g = lane >> 4;
  const int m = t >> 2, h = (t & 3) * 16 + q;
  const float* W = (m == 0) ? Wk : (m == 1) ? Wq : Wv;
  const float sc = (m == 1) ? QSCALE : 1.f;
  const int e0 = ks * 32 + g * 8;
  unsigned short v[8];
  #pragma unroll
  for (int j = 0; j < 8; ++j) v[j] = f2bf(W[(e0 + j) * 64 + h] * sc);
  *(short8*)&Wf[(size_t)idx * 8] = *(short8*)v;
}

// ---------- QKV projection: 32 rows/block; outputs packed for 32x32 attn ---
// kf/qf[b][t32][hs][lane32][8]: elem(row=lane&31, h=hs*16+(lane>>5)*8+j)
// vf[b][t32][htile][ks][lane32][8]: elem(h=(lane&31)+32*htile, key=ks*16+(lane>>5)*8+j)
__global__ __launch_bounds__(256) void qkv_proj(
    const float* __restrict__ x,
    const float* __restrict__ bk, const float* __restrict__ bq,
    const float* __restrict__ bv, const unsigned short* __restrict__ Wf,
    unsigned short* __restrict__ kf, unsigned short* __restrict__ qf,
    unsigned short* __restrict__ vf) {
  __shared__ alignas(16) unsigned short xs[2][32][264];

  const int tid = threadIdx.x;
  const long row0 = (long)blockIdx.x * 32;
  const int w = tid >> 6, lane = tid & 63;
  const int q = lane & 15, g = lane >> 4;

  const float4* xg = (const float4*)&x[row0 * EE];  // 32 rows x 256 f4

  #pragma unroll
  for (int i = 0; i < 8; ++i) {
    const int flat = i * 256 + tid;
    const int rr = flat >> 6, c4 = flat & 63;
    const float4 xv = xg[rr * 256 + c4];
    us4 pk = {f2bf(xv.x), f2bf(xv.y), f2bf(xv.z), f2bf(xv.w)};
    *(us4*)&xs[0][rr][c4 * 4] = pk;
  }
  __syncthreads();

  const f32x4 z = {0.f, 0.f, 0.f, 0.f};
  f32x4 acc00 = z, acc01 = z, acc02 = z;
  f32x4 acc10 = z, acc11 = z, acc12 = z;
  const unsigned short* wf0 = &Wf[(size_t)(3 * w) * 16384 + (size_t)lane * 8];

  float4 st[8];
  #pragma unroll
  for (int cc = 0; cc < 4; ++cc) {
    if (cc < 3) {
      #pragma unroll
      for (int i = 0; i < 8; ++i) {
        const int flat = i * 256 + tid;
        const int rr = flat >> 6, c4 = flat & 63;
        st[i] = xg[rr * 256 + (cc + 1) * 64 + c4];
      }
    }
    #pragma unroll
    for (int ksl = 0; ksl < 8; ++ksl) {
      const short8 a0 = *(const short8*)&xs[cc & 1][q][ksl * 32 + g * 8];
      const short8 a1 = *(const short8*)&xs[cc & 1][16 + q][ksl * 32 + g * 8];
      const int ks = cc * 8 + ksl;
      const short8 b0 = *(const short8*)&wf0[ks * 512];
      const short8 b1 = *(const short8*)&wf0[16384 + ks * 512];
      const short8 b2 = *(const short8*)&wf0[32768 + ks * 512];
      acc00 = __builtin_amdgcn_mfma_f32_16x16x32_bf16(a0, b0, acc00, 0, 0, 0);
      acc10 = __builtin_amdgcn_mfma_f32_16x16x32_bf16(a1, b0, acc10, 0, 0, 0);
      acc01 = __builtin_amdgcn_mfma_f32_16x16x32_bf16(a0, b1, acc01, 0, 0, 0);
      acc11 = __builtin_amdgcn_mfma_f32_16x16x32_bf16(a1, b1, acc11, 0, 0, 0);
      acc02 = __builtin_amdgcn_mfma_f32_16x16x32_bf16(a0, b2, acc02, 0, 0, 0);
      acc12 = __builtin_amdgcn_mfma_f32_16x16x32_bf16(a1, b2, acc12, 0, 0, 0);
    }
    if (cc < 3) {
      #pragma unroll
      for (int i = 0; i < 8; ++i) {
        const int flat = i * 256 + tid;
        const int rr = flat >> 6, c4 = flat & 63;
        us4 pk = {f2bf(st[i].x), f2bf(st[i].y), f2bf(st[i].z), f2bf(st[i].w)};
        *(us4*)&xs[(cc + 1) & 1][rr][c4 * 4] = pk;
      }
    }
    __syncthreads();
  }

  // epilogue: D[row=4g+r][col=q], h = hb*16+q; pack for 32x32 fragments
  const long bidx = row0 >> 11;
  const int tl0 = (int)(row0 & 2047);
  #pragma unroll
  for (int i = 0; i < 3; ++i) {
    const int tgl = 3 * w + i;
    const int mm = tgl >> 2, hb = tgl & 3;
    const int h = hb * 16 + q;
    const float bias = (mm == 0) ? bk[h] : (mm == 1) ? bq[h] * QSCALE : bv[h];
    #pragma unroll
    for (int stp = 0; stp < 2; ++stp) {
      const f32x4 a = (stp == 0) ? ((i == 0) ? acc00 : (i == 1) ? acc01 : acc02)
                                 : ((i == 0) ? acc10 : (i == 1) ? acc11 : acc12);
      #pragma unroll
      for (int r = 0; r < 4; ++r) {
        const int tl = tl0 + stp * 16 + 4 * g + r;
        const unsigned short ov = f2bf(a[r] + bias);
        if (mm == 2) {
          const int lane32v = ((hb & 1) * 16 + q) + 32 * ((tl >> 3) & 1);
          const size_t vidx = (size_t)bidx * 131072 + (size_t)(tl >> 5) * 2048 +
                              (size_t)(hb >> 1) * 1024 +
                              (size_t)((tl >> 4) & 1) * 512 +
                              (size_t)lane32v * 8 + (size_t)(tl & 7);
          vf[vidx] = ov;
        } else {
          const int lane32 = (tl & 31) + 32 * ((q >> 3) & 1);
          const size_t kqidx = (size_t)bidx * 131072 + (size_t)(tl >> 5) * 2048 +
                               (size_t)hb * 512 + (size_t)lane32 * 8 +
                               (size_t)(q & 7);
          if (mm == 0) kf[kqidx] = ov; else qf[kqidx] = ov;
        }
      }
    }
  }
}

// ---------- flash attention: 32x32 MFMA, 32-q strips, paired blocks --------
// S^T = mfma32(K, Q): lane(q=lane&31, hf=lane>>5) holds 16 keys of column q.
// P^T redistribution: 8 cvt_pk + 4 shfl_xor(32) + selects (no LDS, no bpermute).
#define BODY(KC, KN, tt, PREF) do {                                          \
    const unsigned short* vp_ = vfb + (size_t)(tt) * 2048;                   \
    const short8 V00 = *(const short8*)&vp_[0];                              \
    const short8 V01 = *(const short8*)&vp_[512];                            \
    const short8 V10 = *(const short8*)&vp_[1024];                           \
    const short8 V11 = *(const short8*)&vp_[1536];                           \
    if (PREF) {                                                              \
      const unsigned short* kp_ = kfb + (size_t)((tt) + stride) * 2048;      \
      KN[0] = *(const short8*)&kp_[0];                                       \
      KN[1] = *(const short8*)&kp_[512];                                     \
      KN[2] = *(const short8*)&kp_[1024];                                    \
      KN[3] = *(const short8*)&kp_[1536];                                    \
    }                                                                        \
    f32x16 S;                                                                \
    _Pragma("unroll")                                                        \
    for (int r = 0; r < 16; ++r) S[r] = 0.f;                                 \
    S = __builtin_amdgcn_mfma_f32_32x32x16_bf16(KC[0], Qf0, S, 0, 0, 0);     \
    S = __builtin_amdgcn_mfma_f32_32x32x16_bf16(KC[1], Qf1, S, 0, 0, 0);     \
    S = __builtin_amdgcn_mfma_f32_32x32x16_bf16(KC[2], Qf2, S, 0, 0, 0);     \
    S = __builtin_amdgcn_mfma_f32_32x32x16_bf16(KC[3], Qf3, S, 0, 0, 0);     \
    const int k0_ = (tt) * 32;                                               \
    if (k0_ + 31 > q0) {                                                     \
      _Pragma("unroll")                                                      \
      for (int r = 0; r < 16; ++r) {                                         \
        const int key = (r & 3) + 8 * (r >> 2) + 4 * hf;                     \
        if (k0_ + key > qg) S[r] = -INFINITY;                                \
      }                                                                      \
    }                                                                        \
    float pmax = S[0];                                                       \
    _Pragma("unroll")                                                        \
    for (int r = 1; r < 16; ++r) pmax = fmaxf(pmax, S[r]);                   \
    if (!__all(pmax <= m + 8.0f)) {                                          \
      const float pm2 = fmaxf(pmax, __shfl_xor(pmax, 32));                   \
      const float nm = fmaxf(m, pm2);                                        \
      const float rs = __builtin_amdgcn_exp2f(m - nm);                       \
      l *= rs;                                                               \
      _Pragma("unroll")                                                      \
      for (int r = 0; r < 16; ++r) { O0[r] *= rs; O1[r] *= rs; }             \
      m = nm;                                                                \
    }                                                                        \
    float P[16]; float ps = 0.f;                                             \
    _Pragma("unroll")                                                        \
    for (int r = 0; r < 16; ++r) {                                           \
      P[r] = __builtin_amdgcn_exp2f(S[r] - m); ps += P[r];                   \
    }                                                                        \
    l += ps;                                                                 \
    unsigned wa0, wa1, wa2, wa3, wb0, wb1, wb2, wb3;                         \
    asm("v_cvt_pk_bf16_f32 %0, %1, %2" : "=v"(wa0) : "v"(P[0]), "v"(P[1])); \
    asm("v_cvt_pk_bf16_f32 %0, %1, %2" : "=v"(wb0) : "v"(P[2]), "v"(P[3])); \
    asm("v_cvt_pk_bf16_f32 %0, %1, %2" : "=v"(wa1) : "v"(P[4]), "v"(P[5])); \
    asm("v_cvt_pk_bf16_f32 %0, %1, %2" : "=v"(wb1) : "v"(P[6]), "v"(P[7])); \
    asm("v_cvt_pk_bf16_f32 %0, %1, %2" : "=v"(wa2) : "v"(P[8]), "v"(P[9])); \
    asm("v_cvt_pk_bf16_f32 %0, %1, %2" : "=v"(wb2) : "v"(P[10]), "v"(P[11]));\
    asm("v_cvt_pk_bf16_f32 %0, %1, %2" : "=v"(wa3) : "v"(P[12]), "v"(P[13]));\
    asm("v_cvt_pk_bf16_f32 %0, %1, %2" : "=v"(wb3) : "v"(P[14]), "v"(P[15]));\
    { /* ks=0: dest needs u = hf; self keeps u=hf, sends u=hf^1 */           \
      const unsigned sA = hf ? wa1 : wa0, sB = hf ? wb1 : wb0;               \
      const unsigned tA = hf ? wa0 : wa1, tB = hf ? wb0 : wb1;               \
      const unsigned xA = __shfl_xor((int)tA, 32);                           \
      const unsigned xB = __shfl_xor((int)tB, 32);                           \
      union { unsigned u[4]; short8 s; } pf_;                                \
      pf_.u[0] = hf ? xA : sA; pf_.u[1] = hf ? xB : sB;                      \
      pf_.u[2] = hf ? sA : xA; pf_.u[3] = hf ? sB : xB;                      \
      O0 = __builtin_amdgcn_mfma_f32_32x32x16_bf16(V00, pf_.s, O0, 0, 0, 0); \
      O1 = __builtin_amdgcn_mfma_f32_32x32x16_bf16(V10, pf_.s, O1, 0, 0, 0); \
    }                                                                        \
    { /* ks=1: u = 2 + hf */                                                 \
      const unsigned sA = hf ? wa3 : wa2, sB = hf ? wb3 : wb2;               \
      const unsigned tA = hf ? wa2 : wa3, tB = hf ? wb2 : wb3;               \
      const unsigned xA = __shfl_xor((int)tA, 32);                           \
      const unsigned xB = __shfl_xor((int)tB, 32);                           \
      union { unsigned u[4]; short8 s; } pf_;                                \
      pf_.u[0] = hf ? xA : sA; pf_.u[1] = hf ? xB : sB;                      \
      pf_.u[2] = hf ? sA : xA; pf_.u[3] = hf ? sB : xB;                      \
      O0 = __builtin_amdgcn_mfma_f32_32x32x16_bf16(V01, pf_.s, O0, 0, 0, 0); \
      O1 = __builtin_amdgcn_mfma_f32_32x32x16_bf16(V11, pf_.s, O1, 0, 0, 0); \
    }                                                                        \
  } while (0)

__global__ __launch_bounds__(512) void attn_fwd(
    const unsigned short* __restrict__ qf, const unsigned short* __restrict__ kf,
    const unsigned short* __restrict__ vf, float* __restrict__ out) {
  __shared__ float accS[8][32][65];
  __shared__ float mlS[8][2][32];

  const int tid = threadIdx.x;
  const int w = tid >> 6, lane = tid & 63;
  const int q = lane & 31, hf = lane >> 5;

  const int b = blockIdx.x & 7;
  const int p = blockIdx.x >> 3;          // pair 0..31 (strips of 32 rows)
  const int s1 = 63 - p;
  const int nt0 = p + 1, nt1 = 64 - p;    // 32-key tiles; nt0+nt1 = 65
  int k = (8 * nt0 + 32) / 65;
  if (k < 1) k = 1;
  if (k > 7) k = 7;

  const bool onS0 = (w < k);
  const int s = onS0 ? p : s1;
  const int nt = onS0 ? nt0 : nt1;
  const int stride = onS0 ? k : (8 - k);
  int t = onS0 ? w : (w - k);

  const int q0 = s * 32;
  const int qg = q0 + q;

  const unsigned short* kfb = kf + (size_t)b * 131072 + (size_t)lane * 8;
  const unsigned short* vfb = vf + (size_t)b * 131072 + (size_t)lane * 8;
  const unsigned short* qfb = qf + (size_t)b * 131072 + (size_t)s * 2048 +
                              (size_t)lane * 8;
  const short8 Qf0 = *(const short8*)&qfb[0];
  const short8 Qf1 = *(const short8*)&qfb[512];
  const short8 Qf2 = *(const short8*)&qfb[1024];
  const short8 Qf3 = *(const short8*)&qfb[1536];

  float m = -3.0e38f, l = 0.f;
  f32x16 O0, O1;
  #pragma unroll
  for (int r = 0; r < 16; ++r) { O0[r] = 0.f; O1[r] = 0.f; }

  {
    short8 A[4], B[4];
    const unsigned short* kp0 = kfb + (size_t)t * 2048;
    A[0] = *(const short8*)&kp0[0];
    A[1] = *(const short8*)&kp0[512];
    A[2] = *(const short8*)&kp0[1024];
    A[3] = *(const short8*)&kp0[1536];
    for (;;) {
      bool pf = (t + stride) < nt;
      BODY(A, B, t, pf);
      if (!pf) break;
      t += stride;
      pf = (t + stride) < nt;
      BODY(B, A, t, pf);
      if (!pf) break;
      t += stride;
    }
  }

  // per-wave state: l merged across halves; m already column-wide
  const float lq = l + __shfl_xor(l, 32);
  #pragma unroll
  for (int r = 0; r < 16; ++r) {
    const int hh0 = (r & 3) + 8 * (r >> 2) + 4 * hf;
    accS[w][q][hh0] = O0[r];
    accS[w][q][hh0 + 32] = O1[r];
  }
  if (hf == 0) { mlS[w][0][q] = m; mlS[w][1][q] = lq; }
  __syncthreads();

  // merge: tid<256 -> strip p (waves 0..k-1), tid>=256 -> strip s1 (k..7)
  const int half_t = tid >> 8;
  const int sm = half_t ? s1 : p;
  const int lo = half_t ? k : 0, hi2 = half_t ? 8 : k;
  const int hh = tid & 63;
  const int qb0 = (tid >> 6) & 3;
  const long obase = ((long)b * TT + (long)sm * 32) * 64;
  #pragma unroll
  for (int kk = 0; kk < 8; ++kk) {
    const int qv = qb0 + 4 * kk;
    float M = -INFINITY;
    for (int i = lo; i < hi2; ++i) M = fmaxf(M, mlS[i][0][qv]);
    float L = 0.f, acc = 0.f;
    for (int i = lo; i < hi2; ++i) {
      const float fi = __builtin_amdgcn_exp2f(mlS[i][0][qv] - M);
      L += fi * mlS[i][1][qv];
      acc += fi * accS[i][qv][hh];
    }
    out[obase + (long)qv * 64 + hh] = acc / L;
  }
}

extern "C" void kernel_launch(void* const* d_in, const int* in_sizes, int n_in,
                              void* d_out, int out_size, void* d_ws, size_t ws_size,
                              hipStream_t stream) {
  const float* x  = (const float*)d_in[0];
  const float* Wk = (const float*)d_in[1];
  const float* bk = (const float*)d_in[2];
  const float* Wq = (const float*)d_in[3];
  const float* bq = (const float*)d_in[4];
  const float* Wv = (const float*)d_in[5];
  const float* bv = (const float*)d_in[6];
  float* out = (float*)d_out;

  unsigned short* qfb = (unsigned short*)d_ws;             // [B][64 strips][2048]
  unsigned short* kfb = qfb + (size_t)1048576;             // [B][64 tiles][2048]
  unsigned short* vfb = kfb + (size_t)1048576;             // [B][64 tiles][2048]
  unsigned short* Wf  = vfb + (size_t)1048576;             // [12][32][64][8]

  prep_w<<<dim3(96), 256, 0, stream>>>(Wk, Wq, Wv, Wf);
  qkv_proj<<<dim3(512), 256, 0, stream>>>(x, bk, bq, bv, Wf, kfb, qfb, vfb);
  attn_fwd<<<dim3(256), 512, 0, stream>>>(qfb, kfb, vfb, out);
}